// Round 11
// baseline (267.968 us; speedup 1.0000x reference)
//
#include <hip/hip_runtime.h>

#define B_   64
#define E_   1024
#define N_   512
#define D_   64
#define HID_ 128
#define T_   5

typedef __bf16 bf16x8 __attribute__((ext_vector_type(8)));
typedef float f32x4 __attribute__((ext_vector_type(4)));

__device__ __forceinline__ unsigned short f2bu(float f) {
    union { float f; unsigned int u; } v; v.f = f;
    unsigned int r = (v.u + 0x7fffu + ((v.u >> 16) & 1u)) >> 16;  // RNE
    return (unsigned short)r;
}

__device__ __forceinline__ unsigned int pack2(float lo, float hi) {
    union { __bf16 b[2]; unsigned int u; } v;
    v.b[0] = (__bf16)lo; v.b[1] = (__bf16)hi;   // RNE
    return v.u;
}

__device__ __forceinline__ uint4 cvt8(float4 a, float4 b) {
    union { __bf16 h[8]; uint4 u; } v;
    v.h[0] = (__bf16)a.x; v.h[1] = (__bf16)a.y; v.h[2] = (__bf16)a.z; v.h[3] = (__bf16)a.w;
    v.h[4] = (__bf16)b.x; v.h[5] = (__bf16)b.y; v.h[6] = (__bf16)b.z; v.h[7] = (__bf16)b.w;
    return v.u;
}

#define MFMA16(a, b, c) __builtin_amdgcn_mfma_f32_16x16x32_bf16((a), (b), (c), 0, 0, 0)

// Raw barrier: LDS-visibility only, NO vmcnt drain (validated R10).
#define RBAR() do {                                          \
    __builtin_amdgcn_sched_barrier(0);                       \
    asm volatile("s_waitcnt lgkmcnt(0)" ::: "memory");       \
    __builtin_amdgcn_s_barrier();                            \
    __builtin_amdgcn_sched_barrier(0);                       \
} while (0)

// ---------------------------------------------------------------------------
// Merged prep (one launch): blocks [0,320) do the W transpose/cvt; blocks
// [320,832) do the ori transpose + out concat-half. Bodies verbatim.
// ---------------------------------------------------------------------------
__global__ __launch_bounds__(256) void k_prep(const float* __restrict__ W1,
                                              const float* __restrict__ W2,
                                              const float* __restrict__ ori,
                                              unsigned short* __restrict__ W1T,
                                              unsigned short* __restrict__ W2T,
                                              float* __restrict__ out,
                                              unsigned short* __restrict__ oriT) {
    __shared__ float tl[64 * 65];
    int tid = threadIdx.x;
    if (blockIdx.x < 320) {
        int idx = blockIdx.x * 256 + tid;
        if (idx < T_ * HID_ * D_) {
            int t = idx / (HID_ * D_), rem = idx % (HID_ * D_);
            int h = rem / D_, d = rem % D_;
            W1T[idx] = f2bu(W1[(t * D_ + d) * HID_ + h]);
        } else {
            int j = idx - T_ * HID_ * D_;
            int t = j / (D_ * HID_), rem = j % (D_ * HID_);
            int d = rem / HID_, h = rem % HID_;
            W2T[j] = f2bu(W2[(t * HID_ + h) * D_ + d]);
        }
        return;
    }
    int id = blockIdx.x - 320;
    int b = id >> 3, n0 = (id & 7) * 64;
    int dl = tid & 63;
    #pragma unroll 4
    for (int p = 0; p < 16; ++p) {
        int nn = p * 4 + (tid >> 6);
        float v = ori[(size_t)(b * N_ + n0 + nn) * D_ + dl];
        out[(size_t)(b * N_ + n0 + nn) * 128 + 64 + dl] = v;
        tl[dl * 65 + nn] = v;
    }
    __syncthreads();
    #pragma unroll 4
    for (int p = 0; p < 16; ++p) {
        int dd = p * 4 + (tid >> 6);
        oriT[(size_t)(b * D_ + dd) * N_ + n0 + dl] = f2bu(tl[dd * 65 + dl]);
    }
}

// ---------------------------------------------------------------------------
// Fused K1+K2, v10 = v9 (R10-passing, 84.7us) + three changes:
//   (a) depth-2 register prefetch of the H (HBM) staging loads: H(ks+2)
//       issued at step ks -> a full interval in flight before the vmcnt
//       wait at the ds_write. oriT loads stay depth-1 (L2-hot).
//   (b) a_sh aliased into X buf0 (dead after ks=6's RBAR; afr reads fenced
//       by the existing RBAR before weight writes). LDS 62464 -> 54272 B
//       -> 3 blocks/CU (12 waves, +50% TLP).
//   (c) __launch_bounds__(256,3) to cap VGPR for the 3rd block.
//   Phase 2 verbatim from v9.
// ---------------------------------------------------------------------------
__global__ __launch_bounds__(256, 3) void k_edge_mlp(const float* __restrict__ H,
                                                     const unsigned short* __restrict__ oriT,
                                                     const float* __restrict__ ed,
                                                     const float* __restrict__ b1,
                                                     const float* __restrict__ b2,
                                                     const unsigned short* __restrict__ W1T,
                                                     const unsigned short* __restrict__ W2T,
                                                     unsigned short* __restrict__ efT) {
    int bx = blockIdx.x;
    int b = bx >> 4, e0 = (bx & 15) * 64;
    // X (16384 shorts = 32 KB):
    //   phase 1: buf0 {aA@0, bB@4096}, buf1 {aA@8192, bB@12288}  (64x64 each)
    //   interlude: a_sh aliases X[0,4096)
    //   phase 2: w1_sh = X[0,8192) (128x64 swz), w2_sh = X[8192,16384) (64x128 swz)
    __shared__ __align__(16) unsigned short X[16384];
    __shared__ __align__(16) unsigned short h_sh[64 * 128];  // wave-own, swizzled
    __shared__ float wd_sh[320];
    __shared__ float b1_sh[640];
    __shared__ float b2_sh[320];
    int tid = threadIdx.x, w = tid >> 6, l = tid & 63, q = l >> 4, c = l & 15;
    int rs = tid >> 3, sgs = tid & 7;
    int swsl = (sgs ^ (rs & 7)) * 8;          // swizzled slot; (rs+32)&7 == rs&7

    for (int u = tid; u < 320; u += 256) wd_sh[u] = ed[((size_t)b * E_ + e0) * T_ + u];
    for (int u = tid; u < 640; u += 256) b1_sh[u] = b1[u];
    for (int u = tid; u < 320; u += 256) b2_sh[u] = b2[u];

    const f32x4 zero = {0.f, 0.f, 0.f, 0.f};

    f32x4 acc1[4];
    #pragma unroll
    for (int fn = 0; fn < 4; ++fn) acc1[fn] = zero;

    const float* Hb = &H[((size_t)b * E_ + e0) * N_];
    const unsigned short* Ob = &oriT[(size_t)b * D_ * N_];

    // H prefetch register sets (depth-2): data(k) lives in set k&1 (A=0,B=1)
    float4 hA0, hA1, hA2, hA3;
    float4 hB0, hB1, hB2, hB3;
    uint4 or0, or1;           // oriT depth-1
    uint4 wr1[4], wr2[4];     // phase-2 weight prefetch

#define P1_LOADH(F0, F1, F2, F3, k0) do {                                     \
        const float* s0_ = Hb + (size_t)rs * N_ + (k0) + sgs * 8;             \
        const float* s1_ = Hb + (size_t)(rs + 32) * N_ + (k0) + sgs * 8;      \
        F0 = *(const float4*)&s0_[0]; F1 = *(const float4*)&s0_[4];           \
        F2 = *(const float4*)&s1_[0]; F3 = *(const float4*)&s1_[4];           \
    } while (0)
#define P1_LOADO(k0) do {                                                     \
        or0 = *(const uint4*)&Ob[(size_t)rs * N_ + (k0) + sgs * 8];           \
        or1 = *(const uint4*)&Ob[(size_t)(rs + 32) * N_ + (k0) + sgs * 8];    \
    } while (0)
#define P1_WRITE(bufi, F0, F1, F2, F3) do {                                   \
        unsigned short* aW_ = X + (bufi) * 8192;                              \
        unsigned short* bW_ = aW_ + 4096;                                     \
        *(uint4*)&aW_[rs * 64 + swsl] = cvt8(F0, F1);                         \
        *(uint4*)&aW_[(rs + 32) * 64 + swsl] = cvt8(F2, F3);                  \
        *(uint4*)&bW_[rs * 64 + swsl] = or0;                                  \
        *(uint4*)&bW_[(rs + 32) * 64 + swsl] = or1;                           \
    } while (0)

    // prologue: H(0)->A, H(1)->B, O(0); write buf0 from {A, O(0)}
    P1_LOADH(hA0, hA1, hA2, hA3, 0);
    P1_LOADH(hB0, hB1, hB2, hB3, 64);
    P1_LOADO(0);
    P1_WRITE(0, hA0, hA1, hA2, hA3);
    RBAR();

    #pragma unroll
    for (int ks = 0; ks < 8; ++ks) {
        if (ks < 6) {  // H(ks+2) -> set ks&1 (freed by write at step ks-1)
            if ((ks & 1) == 0) P1_LOADH(hA0, hA1, hA2, hA3, (ks + 2) * 64);
            else               P1_LOADH(hB0, hB1, hB2, hB3, (ks + 2) * 64);
        }
        if (ks < 7) P1_LOADO((ks + 1) * 64);
        if (ks == 7) {  // t=0 weight loads; fly through the interlude
            #pragma unroll
            for (int p = 0; p < 4; ++p) {
                int u2 = p * 256 + tid;
                wr1[p] = *(const uint4*)&W1T[(size_t)(u2 >> 3) * D_ + (u2 & 7) * 8];
                wr2[p] = *(const uint4*)&W2T[(size_t)(u2 >> 4) * HID_ + (u2 & 15) * 8];
            }
        }
        const unsigned short* aA = X + (ks & 1) * 8192;
        const unsigned short* bB = aA + 4096;
        #pragma unroll
        for (int hh = 0; hh < 2; ++hh) {
            int sl = ((hh * 4 + q) ^ (c & 7)) * 8;
            bf16x8 a0 = *(const bf16x8*)&aA[(w * 16 + c) * 64 + sl];
            #pragma unroll
            for (int fn = 0; fn < 4; ++fn) {
                bf16x8 bb = *(const bf16x8*)&bB[(fn * 16 + c) * 64 + sl];
                acc1[fn] = MFMA16(a0, bb, acc1[fn]);
            }
        }
        if (ks < 7) {  // write buf (ks+1)&1 from H set (ks+1)&1 + O(ks+1)
            if (((ks + 1) & 1) == 0) P1_WRITE(0, hA0, hA1, hA2, hA3);
            else                     P1_WRITE(1, hB0, hB1, hB2, hB3);
            RBAR();
        }
    }

    // a_sh aliases X[0,4096): buf0 dead since ks=6's RBAR; ks=7 read buf1.
    // wave-own rows (write w*16+q*4+i, read w*16+c), swizzled.
    unsigned short* a_sh = X;
    #pragma unroll
    for (int fn = 0; fn < 4; ++fn)
        #pragma unroll
        for (int i = 0; i < 4; ++i) {
            int row = w * 16 + q * 4 + i;
            a_sh[row * 64 + ((fn * 16 + c) ^ ((row & 7) << 3))] = f2bu(acc1[fn][i]);
        }
    bf16x8 afr[2];
    #pragma unroll
    for (int ks2 = 0; ks2 < 2; ++ks2)
        afr[ks2] = *(const bf16x8*)&a_sh[(w * 16 + c) * 64 + (((ks2 * 4 + q) ^ (c & 7)) * 8)];

    RBAR();  // all waves' X reads (ks=7 MFMA + afr) done before weight writes

    unsigned short* w1_sh = X;            // 128 x 64 swz
    unsigned short* w2_sh = X + 8192;     // 64 x 128 swz

    // ---- Phase 2: per-type MLP + mixture (v9-verbatim, 2 raw barriers/t) ----
    f32x4 y[4];
    #pragma unroll
    for (int fn = 0; fn < 4; ++fn) y[fn] = zero;

    #pragma unroll
    for (int t = 0; t < T_; ++t) {
        #pragma unroll
        for (int p = 0; p < 4; ++p) {
            int u2 = p * 256 + tid, hh = u2 >> 3, sg = u2 & 7;
            *(uint4*)&w1_sh[hh * 64 + ((sg ^ (hh & 7)) * 8)] = wr1[p];
        }
        #pragma unroll
        for (int p = 0; p < 4; ++p) {
            int u2 = p * 256 + tid, dd = u2 >> 4, sg = u2 & 15;
            *(uint4*)&w2_sh[dd * 128 + ((sg ^ (dd & 7)) * 8)] = wr2[p];
        }
        RBAR();  // B1: weights visible
        if (t < T_ - 1) {
            #pragma unroll
            for (int p = 0; p < 4; ++p) {
                int u2 = p * 256 + tid;
                wr1[p] = *(const uint4*)&W1T[((size_t)(t + 1) * HID_ + (u2 >> 3)) * D_ + (u2 & 7) * 8];
                wr2[p] = *(const uint4*)&W2T[((size_t)(t + 1) * D_ + (u2 >> 4)) * HID_ + (u2 & 15) * 8];
            }
        }
        f32x4 hc[8];
        #pragma unroll
        for (int fn = 0; fn < 8; ++fn) hc[fn] = zero;
        #pragma unroll
        for (int ks2 = 0; ks2 < 2; ++ks2) {
            #pragma unroll
            for (int fn = 0; fn < 8; ++fn) {
                bf16x8 bb = *(const bf16x8*)&w1_sh[(fn * 16 + c) * 64 + (((ks2 * 4 + q) ^ (c & 7)) * 8)];
                hc[fn] = MFMA16(afr[ks2], bb, hc[fn]);
            }
        }
        float wv[4];
        #pragma unroll
        for (int i = 0; i < 4; ++i) wv[i] = wd_sh[(w * 16 + q * 4 + i) * T_ + t];
        #pragma unroll
        for (int fn = 0; fn < 8; ++fn) {
            float b1v = b1_sh[t * HID_ + fn * 16 + c];
            #pragma unroll
            for (int i = 0; i < 4; ++i) {
                float v = hc[fn][i] + b1v;
                v = fmaxf(v, 0.0f) * wv[i];
                int row = q * 4 + i;
                h_sh[(w * 16 + row) * 128 + ((fn * 16 + c) ^ ((row & 7) << 3))] = f2bu(v);
            }
        }
        #pragma unroll
        for (int ks2 = 0; ks2 < 4; ++ks2) {
            bf16x8 a = *(const bf16x8*)&h_sh[(w * 16 + c) * 128 + (((ks2 * 4 + q) ^ (c & 7)) * 8)];
            #pragma unroll
            for (int fn = 0; fn < 4; ++fn) {
                bf16x8 bb = *(const bf16x8*)&w2_sh[(fn * 16 + c) * 128 + (((ks2 * 4 + q) ^ (c & 7)) * 8)];
                y[fn] = MFMA16(a, bb, y[fn]);
            }
        }
        RBAR();  // B2: all waves' w1/w2 reads done before next t's writes
    }

    // epilogue: + sum_t w*b2, write efT[b][d][e] transposed (bf16 ushort4)
    #pragma unroll
    for (int fn = 0; fn < 4; ++fn) {
        int d = fn * 16 + c;
        ushort4 o;
        #pragma unroll
        for (int i = 0; i < 4; ++i) {
            int r = w * 16 + q * 4 + i;
            float s = y[fn][i];
            #pragma unroll
            for (int t = 0; t < T_; ++t) s += wd_sh[r * T_ + t] * b2_sh[t * D_ + d];
            ((unsigned short*)&o)[i] = f2bu(s);
        }
        *(ushort4*)&efT[((size_t)b * D_ + d) * E_ + e0 + w * 16 + q * 4] = o;
    }
#undef P1_LOADH
#undef P1_LOADO
#undef P1_WRITE
}

// ---------------------------------------------------------------------------
// K3: out[b][n][d] = sum_e H[b][e][n] * ef[b][e][d] as outT tile.
// R4-VERBATIM (~15us by ledger decomposition — leave it alone).
// ---------------------------------------------------------------------------
__global__ __launch_bounds__(256) void k_gemm_out(const float* __restrict__ H,
                                                  const unsigned short* __restrict__ efT,
                                                  float* __restrict__ out) {
    int bid = blockIdx.x;
    int swz = (bid & 7) * 64 + (bid >> 3);    // 512 % 8 == 0 -> bijective
    int b = swz >> 3, n0 = (swz & 7) * 64;
    __shared__ __align__(16) unsigned short aA[2][64 * 72];   // efT [d][e]
    __shared__ unsigned int bB32[2][64 * 33];                 // H^T [n][e/2] pair-packed
    int tid = threadIdx.x, w = tid >> 6, l = tid & 63, q = l >> 4, c = l & 15;
    int r2 = tid >> 3, cg = tid & 7;
    const f32x4 zero = {0.f, 0.f, 0.f, 0.f};
    f32x4 acc[4];
    #pragma unroll
    for (int fm = 0; fm < 4; ++fm) acc[fm] = zero;

    const unsigned short* Ab = &efT[(size_t)b * D_ * E_];
    const float* Hb = &H[(size_t)b * E_ * N_ + n0];

    uint4 ar0, ar1;
    float4 f0, f1, g0, g1;
    {   // prologue: ks=0 loads
        ar0 = *(const uint4*)&Ab[(size_t)r2 * E_ + cg * 8];
        ar1 = *(const uint4*)&Ab[(size_t)(r2 + 32) * E_ + cg * 8];
        const float* s0 = Hb + (size_t)(2 * r2) * N_ + cg * 8;
        const float* s1 = s0 + N_;
        f0 = *(const float4*)&s0[0]; f1 = *(const float4*)&s0[4];
        g0 = *(const float4*)&s1[0]; g1 = *(const float4*)&s1[4];
    }
    {   // write buf0
        *(uint4*)&aA[0][r2 * 72 + cg * 8] = ar0;
        *(uint4*)&aA[0][(r2 + 32) * 72 + cg * 8] = ar1;
        float r0a[8] = {f0.x, f0.y, f0.z, f0.w, f1.x, f1.y, f1.z, f1.w};
        float r1a[8] = {g0.x, g0.y, g0.z, g0.w, g1.x, g1.y, g1.z, g1.w};
        #pragma unroll
        for (int j = 0; j < 8; ++j)
            bB32[0][(cg * 8 + j) * 33 + r2] = pack2(r0a[j], r1a[j]);
    }
    __syncthreads();

    for (int ks = 0; ks < 16; ++ks) {
        if (ks < 15) {  // issue next-step loads before compute
            int k0 = (ks + 1) * 64;
            ar0 = *(const uint4*)&Ab[(size_t)r2 * E_ + k0 + cg * 8];
            ar1 = *(const uint4*)&Ab[(size_t)(r2 + 32) * E_ + k0 + cg * 8];
            const float* s0 = Hb + (size_t)(k0 + 2 * r2) * N_ + cg * 8;
            const float* s1 = s0 + N_;
            f0 = *(const float4*)&s0[0]; f1 = *(const float4*)&s0[4];
            g0 = *(const float4*)&s1[0]; g1 = *(const float4*)&s1[4];
        }
        int cur = ks & 1;
        #pragma unroll
        for (int hh = 0; hh < 2; ++hh) {
            union { unsigned int u[4]; bf16x8 v; } bb;
            #pragma unroll
            for (int i = 0; i < 4; ++i)
                bb.u[i] = bB32[cur][(w * 16 + c) * 33 + hh * 16 + q * 4 + i];
            #pragma unroll
            for (int fm = 0; fm < 4; ++fm) {
                bf16x8 afr = *(const bf16x8*)&aA[cur][(fm * 16 + c) * 72 + hh * 32 + q * 8];
                acc[fm] = MFMA16(afr, bb.v, acc[fm]);
            }
        }
        if (ks < 15) {
            int nxt = cur ^ 1;
            *(uint4*)&aA[nxt][r2 * 72 + cg * 8] = ar0;
            *(uint4*)&aA[nxt][(r2 + 32) * 72 + cg * 8] = ar1;
            float r0a[8] = {f0.x, f0.y, f0.z, f0.w, f1.x, f1.y, f1.z, f1.w};
            float r1a[8] = {g0.x, g0.y, g0.z, g0.w, g1.x, g1.y, g1.z, g1.w};
            #pragma unroll
            for (int j = 0; j < 8; ++j)
                bB32[nxt][(cg * 8 + j) * 33 + r2] = pack2(r0a[j], r1a[j]);
            __syncthreads();
        }
    }
    #pragma unroll
    for (int fm = 0; fm < 4; ++fm) {
        *(f32x4*)&out[((size_t)b * N_ + n0 + w * 16 + c) * 128 + fm * 16 + q * 4] = acc[fm];
    }
}

// ---------------------------------------------------------------------------
extern "C" void kernel_launch(void* const* d_in, const int* in_sizes, int n_in,
                              void* d_out, int out_size, void* d_ws, size_t ws_size,
                              hipStream_t stream) {
    const float* ed  = (const float*)d_in[0];  // [B,E,T]
    const float* H   = (const float*)d_in[1];  // [B,E,N]
    const float* ori = (const float*)d_in[2];  // [B,N,64]
    const float* W1  = (const float*)d_in[3];  // [T,64,128]
    const float* b1  = (const float*)d_in[4];  // [T,128]
    const float* W2  = (const float*)d_in[5];  // [T,128,64]
    const float* b2  = (const float*)d_in[6];  // [T,64]
    float* out = (float*)d_out;

    char* ws = (char*)d_ws;
    size_t used = 0;
    unsigned short* oriT = (unsigned short*)(ws + used); used += (size_t)B_ * D_ * N_ * 2;   // 4 MB
    unsigned short* W1T  = (unsigned short*)(ws + used); used += (size_t)T_ * HID_ * D_ * 2;
    unsigned short* W2T  = (unsigned short*)(ws + used); used += (size_t)T_ * D_ * HID_ * 2;
    unsigned short* efT  = (unsigned short*)(ws + used); used += (size_t)B_ * D_ * E_ * 2;   // 8 MB

    hipLaunchKernelGGL(k_prep, dim3(832), dim3(256), 0, stream,
                       W1, W2, ori, W1T, W2T, out, oriT);
    hipLaunchKernelGGL(k_edge_mlp, dim3(1024), dim3(256), 0, stream,
                       H, oriT, ed, b1, b2, W1T, W2T, efT);
    hipLaunchKernelGGL(k_gemm_out, dim3(512), dim3(256), 0, stream, H, efT, out);
}